// Round 1
// baseline (31.583 us; speedup 1.0000x reference)
//
#include <hip/hip_runtime.h>
#include <hip/hip_bf16.h>

#define N_NODES 100000
#define D 128
#define N_EDGES 1000000

// Kernel 1: per-node scores. One wave (64 lanes) per node.
// s[0 .. n_nodes)        = z[n] . W[0:128]   (src score)
// s[n_nodes .. 2n_nodes) = z[n] . W[128:256] (dst score)
__global__ void __launch_bounds__(256) node_scores_kernel(
    const float* __restrict__ z, const float* __restrict__ W,
    float* __restrict__ s, int n_nodes) {
  int gtid = blockIdx.x * blockDim.x + threadIdx.x;
  int node = gtid >> 6;          // wave index == node index
  int lane = threadIdx.x & 63;
  if (node >= n_nodes) return;

  // lane i covers features 2i, 2i+1
  const float2 zv = reinterpret_cast<const float2*>(z + (size_t)node * D)[lane];
  const float2 ws = reinterpret_cast<const float2*>(W)[lane];        // W_src
  const float2 wd = reinterpret_cast<const float2*>(W + D)[lane];    // W_dst

  float a = zv.x * ws.x + zv.y * ws.y;
  float c = zv.x * wd.x + zv.y * wd.y;

  #pragma unroll
  for (int off = 32; off >= 1; off >>= 1) {
    a += __shfl_xor(a, off, 64);
    c += __shfl_xor(c, off, 64);
  }
  if (lane == 0) {
    s[node] = a;
    s[n_nodes + node] = c;
  }
}

// Kernel 2: per-edge sigmoid(s_src[src] + s_dst[dst] + b)
__global__ void __launch_bounds__(256) edge_kernel(
    const int* __restrict__ idx, const float* __restrict__ s,
    const float* __restrict__ b, float* __restrict__ out,
    int n_edges, int n_nodes) {
  int e = blockIdx.x * blockDim.x + threadIdx.x;
  if (e >= n_edges) return;
  int srcn = idx[e];             // edge_index row 0
  int dstn = idx[n_edges + e];   // edge_index row 1
  float logit = s[srcn] + s[n_nodes + dstn] + b[0];
  out[e] = 1.0f / (1.0f + __expf(-logit));
}

extern "C" void kernel_launch(void* const* d_in, const int* in_sizes, int n_in,
                              void* d_out, int out_size, void* d_ws, size_t ws_size,
                              hipStream_t stream) {
  const float* z   = (const float*)d_in[0];
  const int*   idx = (const int*)d_in[1];
  const float* W   = (const float*)d_in[2];
  const float* b   = (const float*)d_in[3];
  float* out = (float*)d_out;
  float* s   = (float*)d_ws;   // 2 * N_NODES floats = 800 KB

  // Kernel 1: 1 wave per node -> 4 nodes per 256-thread block
  int blocks1 = (N_NODES + 3) / 4;
  node_scores_kernel<<<blocks1, 256, 0, stream>>>(z, W, s, N_NODES);

  // Kernel 2: 1 thread per edge
  int blocks2 = (N_EDGES + 255) / 256;
  edge_kernel<<<blocks2, 256, 0, stream>>>(idx, s, b, out, N_EDGES, N_NODES);
}

// Round 2
// 26.367 us; speedup vs baseline: 1.1978x; 1.1978x over previous
//
#include <hip/hip_runtime.h>
#include <hip/hip_bf16.h>

#define N_NODES 100000
#define D 128
#define N_EDGES 1000000

// Kernel 1: per-node scores. 32 lanes per node (float4 loads), 2 nodes/wave.
// s[0 .. n_nodes)        = z[n] . W[0:128] + b   (src score, bias folded in)
// s[n_nodes .. 2n_nodes) = z[n] . W[128:256]     (dst score)
__global__ void __launch_bounds__(256) node_scores_kernel(
    const float* __restrict__ z, const float* __restrict__ W,
    const float* __restrict__ b, float* __restrict__ s, int n_nodes) {
  int wave = (blockIdx.x * blockDim.x + threadIdx.x) >> 6;  // global wave id
  int lane = threadIdx.x & 63;
  int half = lane >> 5;          // which node within the wave
  int l32  = lane & 31;          // lane within the 32-lane group
  int node = wave * 2 + half;
  if (node >= n_nodes) return;

  // lane covers features 4*l32 .. 4*l32+3 (32 lanes x 16B = 512B/node)
  const float4 zv = reinterpret_cast<const float4*>(z + (size_t)node * D)[l32];
  const float4 ws = reinterpret_cast<const float4*>(W)[l32];        // W_src
  const float4 wd = reinterpret_cast<const float4*>(W)[32 + l32];   // W_dst

  float a = zv.x * ws.x + zv.y * ws.y + zv.z * ws.z + zv.w * ws.w;
  float c = zv.x * wd.x + zv.y * wd.y + zv.z * wd.z + zv.w * wd.w;

  // 5-level butterfly within each 32-lane group (off<32 keeps bit 5 fixed)
  #pragma unroll
  for (int off = 16; off >= 1; off >>= 1) {
    a += __shfl_xor(a, off, 64);
    c += __shfl_xor(c, off, 64);
  }
  if (l32 == 0) {
    s[node] = a + b[0];
    s[n_nodes + node] = c;
  }
}

// Kernel 2: 4 edges per thread, sigmoid(s_src[src] + s_dst[dst])
__global__ void __launch_bounds__(256) edge_kernel(
    const int* __restrict__ idx, const float* __restrict__ s,
    float* __restrict__ out, int n_edges, int n_nodes) {
  int t = blockIdx.x * blockDim.x + threadIdx.x;
  if (t * 4 >= n_edges) return;
  const int4 sv = reinterpret_cast<const int4*>(idx)[t];            // src row
  const int4 dv = reinterpret_cast<const int4*>(idx + n_edges)[t];  // dst row
  const float* __restrict__ sd = s + n_nodes;

  float l0 = s[sv.x] + sd[dv.x];
  float l1 = s[sv.y] + sd[dv.y];
  float l2 = s[sv.z] + sd[dv.z];
  float l3 = s[sv.w] + sd[dv.w];

  float4 o;
  o.x = 1.0f / (1.0f + __expf(-l0));
  o.y = 1.0f / (1.0f + __expf(-l1));
  o.z = 1.0f / (1.0f + __expf(-l2));
  o.w = 1.0f / (1.0f + __expf(-l3));
  reinterpret_cast<float4*>(out)[t] = o;
}

extern "C" void kernel_launch(void* const* d_in, const int* in_sizes, int n_in,
                              void* d_out, int out_size, void* d_ws, size_t ws_size,
                              hipStream_t stream) {
  const float* z   = (const float*)d_in[0];
  const int*   idx = (const int*)d_in[1];
  const float* W   = (const float*)d_in[2];
  const float* b   = (const float*)d_in[3];
  float* out = (float*)d_out;
  float* s   = (float*)d_ws;   // 2 * N_NODES floats = 800 KB

  // Kernel 1: 2 nodes per wave, 4 waves per block -> 8 nodes/block
  int blocks1 = (N_NODES + 7) / 8;   // 12500
  node_scores_kernel<<<blocks1, 256, 0, stream>>>(z, W, b, s, N_NODES);

  // Kernel 2: 4 edges per thread
  int blocks2 = (N_EDGES / 4 + 255) / 256;  // 977
  edge_kernel<<<blocks2, 256, 0, stream>>>(idx, s, out, N_EDGES, N_NODES);
}